// Round 1
// baseline (9360.164 us; speedup 1.0000x reference)
//
#include <hip/hip_runtime.h>
#include <stdint.h>

// Problem: N=64, T=128, D=512, H=1024, 4H=4096.
// Decomposition:
//   xwx[n,t,:]  = x[n,t,:]@Wx + b          (precomputed, bf16 MFMA GEMM, 34 GF)
//   P2[n,col,l] = Af[n,:,l]@Wattn[:,col]   (precomputed, bf16 MFMA GEMM, 8.6 GF)
//   per step t:  scores -> softmax w ; a = h@Wh + xwx + sum_l w[l]*P2[..l] ; gates
// Persistent 256-wg kernel, Wh^T slice resident in LDS across all steps,
// c-state in registers, one grid barrier per step, score flags via
// release/acquire agent-scope atomics.

#define Tt 128
#define FH 4096

typedef __bf16 bf8 __attribute__((ext_vector_type(8)));
typedef float f4 __attribute__((ext_vector_type(4)));
typedef short s8v __attribute__((ext_vector_type(8)));

__device__ __forceinline__ float bf2f(unsigned short u) {
    union { unsigned u32; float f; } x; x.u32 = ((unsigned)u) << 16; return x.f;
}
__device__ __forceinline__ unsigned short f2bf(float f) {
    union { float f32; unsigned u; } x; x.f32 = f;
    unsigned r = x.u + 0x7fffu + ((x.u >> 16) & 1u);
    return (unsigned short)(r >> 16);
}

// ---------------- converts / init ----------------

__global__ __launch_bounds__(256) void k_cast_bf16(const float* __restrict__ in,
                                                   unsigned short* __restrict__ out, int n) {
    int i = blockIdx.x * 256 + threadIdx.x;
    if (i < n) out[i] = f2bf(in[i]);
}

// W: [K][4096] f32  ->  WT: [4096][K] bf16
__global__ __launch_bounds__(256) void k_transpose_bf16(const float* __restrict__ W,
                                                        unsigned short* __restrict__ WT, int K) {
    __shared__ float tl[32][33];
    int c0 = blockIdx.x * 32, k0 = blockIdx.y * 32;
    int tx = threadIdx.x & 31, ty = threadIdx.x >> 5;
    #pragma unroll
    for (int i = 0; i < 32; i += 8) tl[ty + i][tx] = W[(size_t)(k0 + ty + i) * 4096 + c0 + tx];
    __syncthreads();
    #pragma unroll
    for (int i = 0; i < 32; i += 8) WT[(size_t)(c0 + ty + i) * K + k0 + tx] = f2bf(tl[tx][ty + i]);
}

// Afl[(n*16+l)*1024 + k] = bf16(A[n][k][l])   (A: [64][1024][16] f32)
__global__ __launch_bounds__(256) void k_afl(const float* __restrict__ A,
                                             unsigned short* __restrict__ Afl) {
    int idx = blockIdx.x * 256 + threadIdx.x;   // idx = n*16384 + l*1024 + k
    int k = idx & 1023, l = (idx >> 10) & 15, n = idx >> 14;
    Afl[idx] = f2bf(A[((size_t)n * 1024 + k) * 16 + l]);
}

// h0 = mean over 16 locations; c0 = h0 (c init read from hstate[0] by persistent kernel)
__global__ __launch_bounds__(256) void k_init(const float* __restrict__ A,
                                              float* __restrict__ hstate,
                                              unsigned short* __restrict__ hbf) {
    int idx = blockIdx.x * 256 + threadIdx.x;   // 64*1024
    const float* ap = A + (size_t)idx * 16;
    float s = 0.f;
    #pragma unroll
    for (int l = 0; l < 16; l++) s += ap[l];
    float h = s * (1.0f / 16.0f);
    hstate[idx] = h;
    hbf[idx] = f2bf(h);
}

// ---------------- generic bf16 MFMA GEMM: out = A[M][K] * BT[N][K]^T (+bias) ----------------
// mode 0: out[row*Nn+col] ; mode 1: row=(n*16+l) -> out[(n*Nn+col)*16+l]  (P2 layout)
__global__ __launch_bounds__(256) void k_gemm(const unsigned short* __restrict__ A,
                                              const unsigned short* __restrict__ BT,
                                              const float* __restrict__ bias,
                                              unsigned short* __restrict__ out,
                                              int M, int Nn, int K, int mode) {
    __shared__ unsigned short As[128][40];   // +8 pad -> 80B rows, 2-way bank alias (free)
    __shared__ unsigned short Bs[128][40];
    int m0 = blockIdx.y * 128, n0 = blockIdx.x * 128;
    int tid = threadIdx.x, lane = tid & 63, wave = tid >> 6;
    int wr = wave >> 1, wc = wave & 1, quad = lane >> 4, l16 = lane & 15;
    f4 acc[4][4];
    #pragma unroll
    for (int i = 0; i < 4; i++)
        #pragma unroll
        for (int j = 0; j < 4; j++) acc[i][j] = f4{0.f, 0.f, 0.f, 0.f};

    for (int k0 = 0; k0 < K; k0 += 32) {
        __syncthreads();
        #pragma unroll
        for (int i = 0; i < 2; i++) {
            int idx = i * 256 + tid, r = idx >> 2, c = idx & 3;
            *(s8v*)&As[r][c * 8] = *(const s8v*)&A[(size_t)(m0 + r) * K + k0 + c * 8];
            *(s8v*)&Bs[r][c * 8] = *(const s8v*)&BT[(size_t)(n0 + r) * K + k0 + c * 8];
        }
        __syncthreads();
        bf8 af[4], bfr[4];
        #pragma unroll
        for (int i = 0; i < 4; i++) af[i] = *(const bf8*)&As[wr * 64 + i * 16 + l16][quad * 8];
        #pragma unroll
        for (int j = 0; j < 4; j++) bfr[j] = *(const bf8*)&Bs[wc * 64 + j * 16 + l16][quad * 8];
        #pragma unroll
        for (int i = 0; i < 4; i++)
            #pragma unroll
            for (int j = 0; j < 4; j++)
                acc[i][j] = __builtin_amdgcn_mfma_f32_16x16x32_bf16(af[i], bfr[j], acc[i][j], 0, 0, 0);
    }

    #pragma unroll
    for (int i = 0; i < 4; i++)
        #pragma unroll
        for (int j = 0; j < 4; j++) {
            int row0 = m0 + wr * 64 + i * 16 + quad * 4;
            int col = n0 + wc * 64 + j * 16 + l16;
            float bia = bias ? bias[col] : 0.0f;
            #pragma unroll
            for (int r = 0; r < 4; r++) {
                float v = acc[i][j][r] + bia;
                int rw = row0 + r;
                if (mode == 0) {
                    out[(size_t)rw * Nn + col] = f2bf(v);
                } else {
                    int n = rw >> 4, l = rw & 15;
                    out[((size_t)n * Nn + col) * 16 + l] = f2bf(v);
                }
            }
        }
}

// ---------------- persistent recurrent kernel ----------------
// 256 wgs x 256 thr. wg (R = wid>>7, C = wid&127): rows n in [32R,32R+32), h-cols j in [8C,8C+8),
// a-cols = {g*1024 + 8C + jj : g in 0..3, jj in 0..7} (32 cols). Wh^T slice LDS-resident.
__global__ __launch_bounds__(256, 1) void k_recurrent(
    const float* __restrict__ Afull, const unsigned short* __restrict__ WhT,
    const unsigned short* __restrict__ xwx, const unsigned short* __restrict__ P2,
    float* __restrict__ hstate, unsigned short* __restrict__ hbf,
    float* __restrict__ wbuf, int* __restrict__ wflag, unsigned* __restrict__ barctr,
    float* __restrict__ out) {
    __shared__ unsigned short WhL[32][1032];  // 66 KB, +8 pad -> 2064B rows (2-way alias, free)
    __shared__ unsigned short hL[32][1032];   // 66 KB
    __shared__ float aL[32][33];              // gate exchange
    __shared__ float wL[32][16];              // softmax weights for this wg's rows
    __shared__ float sred[4][16];             // score wave-reduction scratch

    const int wid = blockIdx.x;
    const int R = wid >> 7, C = wid & 127;
    const int tid = threadIdx.x, lane = tid & 63, wave = tid >> 6;
    const int quad = lane >> 4, l16 = lane & 15;
    const int rr = wave >> 1, cc = wave & 1;
    const int n_l = tid & 31, jl = tid >> 5;
    const int myn = R * 32 + n_l, myj = C * 8 + jl;

    // load Wh^T slice once (stays for all 128 steps)
    for (int it = 0; it < 16; ++it) {
        int idx = it * 256 + tid, c = idx >> 7, ch = idx & 127;
        int acol = ((c >> 3) << 10) + C * 8 + (c & 7);
        *(s8v*)&WhL[c][ch * 8] = *(const s8v*)&WhT[(size_t)acol * 1024 + ch * 8];
    }
    float creg = hstate[(size_t)myn * 1024 + myj];   // c0 = h0

    for (int t = 0; t < Tt; ++t) {
        const float* hs = hstate + (size_t)(t & 1) * 65536;
        const unsigned short* hb = hbf + (size_t)(t & 1) * 65536;

        // ---- scores + softmax (wgs 0..63, one per batch row; overlaps others' GEMM) ----
        if (wid < 64) {
            const int n = wid;
            float part[16];
            #pragma unroll
            for (int l = 0; l < 16; l++) part[l] = 0.f;
            const float* hp = hs + (size_t)n * 1024;
            const float* Ap = Afull + (size_t)n * 16384;
            #pragma unroll
            for (int kk = 0; kk < 4; ++kk) {
                int k = tid * 4 + kk;
                float hv = hp[k];
                const float* ap = Ap + (size_t)k * 16;
                #pragma unroll
                for (int l = 0; l < 16; l++) part[l] += hv * ap[l];
            }
            #pragma unroll
            for (int l = 0; l < 16; l++) {
                float v = part[l];
                v += __shfl_down(v, 32, 64); v += __shfl_down(v, 16, 64);
                v += __shfl_down(v, 8, 64);  v += __shfl_down(v, 4, 64);
                v += __shfl_down(v, 2, 64);  v += __shfl_down(v, 1, 64);
                if (lane == 0) sred[wave][l] = v;
            }
            __syncthreads();
            if (tid == 0) {
                float sc[16]; float mx = -1e30f;
                #pragma unroll
                for (int l = 0; l < 16; l++) {
                    sc[l] = (sred[0][l] + sred[1][l] + sred[2][l] + sred[3][l]) * (1.0f / 32.0f);
                    mx = fmaxf(mx, sc[l]);
                }
                float sum = 0.f;
                #pragma unroll
                for (int l = 0; l < 16; l++) { sc[l] = __expf(sc[l] - mx); sum += sc[l]; }
                float inv = 1.0f / sum;
                #pragma unroll
                for (int l = 0; l < 16; l++) wbuf[n * 16 + l] = sc[l] * inv;
                __threadfence();
                __hip_atomic_store(&wflag[n], t + 1, __ATOMIC_RELEASE, __HIP_MEMORY_SCOPE_AGENT);
            }
        }

        // ---- stage this wg's 32 h-rows (bf16) into LDS ----
        for (int it = 0; it < 16; ++it) {
            int idx = it * 256 + tid, r2 = idx >> 7, ch = idx & 127;
            *(s8v*)&hL[r2][ch * 8] = *(const s8v*)&hb[(size_t)(R * 32 + r2) * 1024 + ch * 8];
        }
        __syncthreads();

        // ---- K-loop: h@Wh, one 16x16 tile per wave ----
        f4 acc = {0.f, 0.f, 0.f, 0.f};
        #pragma unroll 8
        for (int ks = 0; ks < 32; ++ks) {
            bf8 a = *(const bf8*)&hL[rr * 16 + l16][ks * 32 + quad * 8];
            bf8 b = *(const bf8*)&WhL[cc * 16 + l16][ks * 32 + quad * 8];
            acc = __builtin_amdgcn_mfma_f32_16x16x32_bf16(a, b, acc, 0, 0, 0);
        }

        // ---- wait for softmax weights of our 32 rows, stage into LDS ----
        if (tid < 32) {
            while (__hip_atomic_load(&wflag[R * 32 + tid], __ATOMIC_ACQUIRE,
                                     __HIP_MEMORY_SCOPE_AGENT) < t + 1)
                __builtin_amdgcn_s_sleep(1);
        }
        __syncthreads();
        #pragma unroll
        for (int i = 0; i < 2; i++) {
            int idx = i * 256 + tid;
            ((float*)wL)[idx] = wbuf[R * 512 + idx];
        }
        __syncthreads();

        // ---- epilogue: + xwx + attention (P-form), write preactivations to LDS ----
        #pragma unroll
        for (int r = 0; r < 4; r++) {
            int nl = rr * 16 + quad * 4 + r;     // local row (D layout: row = quad*4+reg)
            int cl = cc * 16 + l16;              // local col
            int g = cl >> 3, jj = cl & 7;
            int acol = (g << 10) + C * 8 + jj;
            int n = R * 32 + nl;
            float v = acc[r] + bf2f(xwx[((size_t)n * Tt + t) * FH + acol]);
            const unsigned short* pp = P2 + ((size_t)n * FH + acol) * 16;
            s8v p0 = *(const s8v*)pp;
            s8v p1 = *(const s8v*)(pp + 8);
            float s = 0.f;
            #pragma unroll
            for (int l = 0; l < 8; l++) s += wL[nl][l] * bf2f((unsigned short)p0[l]);
            #pragma unroll
            for (int l = 0; l < 8; l++) s += wL[nl][l + 8] * bf2f((unsigned short)p1[l]);
            aL[nl][cl] = v + s;
        }
        __syncthreads();

        // ---- gates: thread owns (n_l, jl); c stays in register ----
        {
            float iv = aL[n_l][jl],      fv = aL[n_l][8 + jl];
            float ov = aL[n_l][16 + jl], gv = aL[n_l][24 + jl];
            float ig = 1.f / (1.f + __expf(-iv));
            float fg = 1.f / (1.f + __expf(-fv));
            float og = 1.f / (1.f + __expf(-ov));
            float gg = tanhf(gv);
            creg = fg * creg + ig * gg;
            float hv = og * tanhf(creg);
            int nb = (t + 1) & 1;
            out[((size_t)myn * Tt + t) * 1024 + myj] = hv;
            hstate[(size_t)nb * 65536 + (size_t)myn * 1024 + myj] = hv;
            hbf[(size_t)nb * 65536 + (size_t)myn * 1024 + myj] = f2bf(hv);
        }

        // ---- grid barrier (monotonic counter; all 256 wgs resident: 1 wg/CU via LDS) ----
        if (t < Tt - 1) {
            __threadfence();
            __syncthreads();
            if (tid == 0) {
                __hip_atomic_fetch_add(barctr, 1u, __ATOMIC_ACQ_REL, __HIP_MEMORY_SCOPE_AGENT);
                unsigned target = 256u * (unsigned)(t + 1);
                while (__hip_atomic_load(barctr, __ATOMIC_ACQUIRE, __HIP_MEMORY_SCOPE_AGENT) < target)
                    __builtin_amdgcn_s_sleep(2);
            }
            __syncthreads();
        }
    }
}

// ---------------- launch ----------------

extern "C" void kernel_launch(void* const* d_in, const int* in_sizes, int n_in,
                              void* d_out, int out_size, void* d_ws, size_t ws_size,
                              hipStream_t stream) {
    const float* x     = (const float*)d_in[0];   // [64][128][512]
    const float* A     = (const float*)d_in[1];   // [64][1024][16]
    const float* Wx    = (const float*)d_in[2];   // [512][4096]
    const float* Wh    = (const float*)d_in[3];   // [1024][4096]
    const float* Wattn = (const float*)d_in[4];   // [1024][4096]
    const float* b     = (const float*)d_in[5];   // [4096]
    float* out = (float*)d_out;
    char* ws = (char*)d_ws;

    // workspace layout (bytes), total ~103 MB
    unsigned short* xbf    = (unsigned short*)(ws);                // 8,388,608   x as bf16
    unsigned short* WxT    = (unsigned short*)(ws + 8388608);      // 4,194,304   Wx^T bf16
    unsigned short* WhT    = (unsigned short*)(ws + 12582912);     // 8,388,608   Wh^T bf16
    unsigned short* WattnT = (unsigned short*)(ws + 20971520);     // 8,388,608   Wattn^T bf16
    unsigned short* Afl    = (unsigned short*)(ws + 29360128);     // 2,097,152   A transposed (n,l,k) bf16
    unsigned short* xwx    = (unsigned short*)(ws + 31457280);     // 67,108,864  x@Wx+b bf16
    unsigned short* P2     = (unsigned short*)(ws + 98566144);     // 8,388,608   P[n][col][l] bf16
    float* hstate          = (float*)(ws + 106954752);             // 524,288     h fp32 x2
    unsigned short* hbf    = (unsigned short*)(ws + 107479040);    // 262,144     h bf16 x2
    float* wbuf            = (float*)(ws + 107741184);             // 4,096       softmax w
    int* wflag             = (int*)(ws + 107745280);               // 256
    unsigned* barctr       = (unsigned*)(ws + 107745536);          // 256

    hipMemsetAsync(ws + 107745280, 0, 512, stream);   // wflag + barctr

    k_cast_bf16<<<16384, 256, 0, stream>>>(x, xbf, 4194304);
    k_transpose_bf16<<<dim3(128, 16), 256, 0, stream>>>(Wx, WxT, 512);
    k_transpose_bf16<<<dim3(128, 32), 256, 0, stream>>>(Wh, WhT, 1024);
    k_transpose_bf16<<<dim3(128, 32), 256, 0, stream>>>(Wattn, WattnT, 1024);
    k_afl<<<4096, 256, 0, stream>>>(A, Afl);
    k_init<<<256, 256, 0, stream>>>(A, hstate, hbf);

    // xwx = x@Wx + b : M=8192, N=4096, K=512
    k_gemm<<<dim3(32, 64), 256, 0, stream>>>(xbf, WxT, b, xwx, 8192, 4096, 512, 0);
    // P = Afl@Wattn : M=1024, N=4096, K=1024, scattered into P2[n][col][l]
    k_gemm<<<dim3(32, 8), 256, 0, stream>>>(Afl, WattnT, nullptr, P2, 1024, 4096, 1024, 1);

    k_recurrent<<<256, 256, 0, stream>>>(A, WhT, xwx, P2, hstate, hbf, wbuf, wflag, barctr, out);
}

// Round 3
// 2856.894 us; speedup vs baseline: 3.2763x; 3.2763x over previous
//
#include <hip/hip_runtime.h>
#include <stdint.h>

// N=64, T=128, D=512, H=1024, 4H=4096.
// R2: per-step kernel launches (stream order = grid barrier). Fix: use
// __builtin_amdgcn_fence for the acquire fence (no __hip_atomic_fence in HIP).
//   xwx[n,t,:]  = x[n,t,:]@Wx + b          (precomputed bf16 MFMA GEMM)
//   P2[n,col,l] = Af[n,:,l]@Wattn[:,col]   (precomputed bf16 MFMA GEMM)
//   k_step(t): scores(from partials)->softmax->flag ; h@Wh direct-from-global
//              MFMA ; epilogue + gates ; write h(t+1), c, partial-scores(t+1)

#define Tt 128
#define FH 4096

typedef __bf16 bf8 __attribute__((ext_vector_type(8)));
typedef float f4 __attribute__((ext_vector_type(4)));
typedef short s8v __attribute__((ext_vector_type(8)));

__device__ __forceinline__ float bf2f(unsigned short u) {
    union { unsigned u32; float f; } x; x.u32 = ((unsigned)u) << 16; return x.f;
}
__device__ __forceinline__ unsigned short f2bf(float f) {
    union { float f32; unsigned u; } x; x.f32 = f;
    unsigned r = x.u + 0x7fffu + ((x.u >> 16) & 1u);
    return (unsigned short)(r >> 16);
}

// ---------------- converts / init ----------------

__global__ __launch_bounds__(256) void k_cast_bf16(const float* __restrict__ in,
                                                   unsigned short* __restrict__ out, int n) {
    int i = blockIdx.x * 256 + threadIdx.x;
    if (i < n) out[i] = f2bf(in[i]);
}

// W: [K][4096] f32  ->  WT: [4096][K] bf16
__global__ __launch_bounds__(256) void k_transpose_bf16(const float* __restrict__ W,
                                                        unsigned short* __restrict__ WT, int K) {
    __shared__ float tl[32][33];
    int c0 = blockIdx.x * 32, k0 = blockIdx.y * 32;
    int tx = threadIdx.x & 31, ty = threadIdx.x >> 5;
    #pragma unroll
    for (int i = 0; i < 32; i += 8) tl[ty + i][tx] = W[(size_t)(k0 + ty + i) * 4096 + c0 + tx];
    __syncthreads();
    #pragma unroll
    for (int i = 0; i < 32; i += 8) WT[(size_t)(c0 + ty + i) * K + k0 + tx] = f2bf(tl[tx][ty + i]);
}

// Afl[(n*16+l)*1024 + k] = bf16(A[n][k][l])
__global__ __launch_bounds__(256) void k_afl(const float* __restrict__ A,
                                             unsigned short* __restrict__ Afl) {
    int idx = blockIdx.x * 256 + threadIdx.x;
    int k = idx & 1023, l = (idx >> 10) & 15, n = idx >> 14;
    Afl[idx] = f2bf(A[((size_t)n * 1024 + k) * 16 + l]);
}

// c0 = h0 = mean over 16 locations; hbf buffer 0 = bf16(h0)
__global__ __launch_bounds__(256) void k_init(const float* __restrict__ A,
                                              float* __restrict__ cstate,
                                              unsigned short* __restrict__ hbf) {
    int idx = blockIdx.x * 256 + threadIdx.x;   // 64*1024
    const float* ap = A + (size_t)idx * 16;
    float s = 0.f;
    #pragma unroll
    for (int l = 0; l < 16; l++) s += ap[l];
    float h = s * (1.0f / 16.0f);
    cstate[idx] = h;
    hbf[idx] = f2bf(h);
}

// scores(0) raw dot: pscore0[n][0][l] = sum_k h0[n,k]*A[n,k,l]  (rest memset 0)
__global__ __launch_bounds__(256) void k_pscore0(const float* __restrict__ A,
                                                 float* __restrict__ pscore0) {
    __shared__ float sred[4][16];
    int n = blockIdx.x, tid = threadIdx.x, lane = tid & 63, wave = tid >> 6;
    float part[16];
    #pragma unroll
    for (int l = 0; l < 16; l++) part[l] = 0.f;
    #pragma unroll
    for (int kk = 0; kk < 4; ++kk) {
        int k = tid * 4 + kk;
        const f4* ar = (const f4*)(A + ((size_t)n * 1024 + k) * 16);
        f4 a0 = ar[0], a1 = ar[1], a2 = ar[2], a3 = ar[3];
        float h = (a0.x+a0.y+a0.z+a0.w + a1.x+a1.y+a1.z+a1.w +
                   a2.x+a2.y+a2.z+a2.w + a3.x+a3.y+a3.z+a3.w) * (1.0f/16.0f);
        const float* af = (const float*)&a0;
        #pragma unroll
        for (int l = 0; l < 4; l++) part[l] += h * af[l];
        af = (const float*)&a1;
        #pragma unroll
        for (int l = 0; l < 4; l++) part[4+l] += h * af[l];
        af = (const float*)&a2;
        #pragma unroll
        for (int l = 0; l < 4; l++) part[8+l] += h * af[l];
        af = (const float*)&a3;
        #pragma unroll
        for (int l = 0; l < 4; l++) part[12+l] += h * af[l];
    }
    #pragma unroll
    for (int l = 0; l < 16; l++) {
        float v = part[l];
        v += __shfl_down(v, 32, 64); v += __shfl_down(v, 16, 64);
        v += __shfl_down(v, 8, 64);  v += __shfl_down(v, 4, 64);
        v += __shfl_down(v, 2, 64);  v += __shfl_down(v, 1, 64);
        if (lane == 0) sred[wave][l] = v;
    }
    __syncthreads();
    if (tid < 16)
        pscore0[(size_t)n * 2048 + tid] = sred[0][tid] + sred[1][tid] + sred[2][tid] + sred[3][tid];
}

// ---------------- generic bf16 MFMA GEMM (preamble) ----------------
__global__ __launch_bounds__(256) void k_gemm(const unsigned short* __restrict__ A,
                                              const unsigned short* __restrict__ BT,
                                              const float* __restrict__ bias,
                                              unsigned short* __restrict__ out,
                                              int M, int Nn, int K, int mode) {
    __shared__ unsigned short As[128][40];
    __shared__ unsigned short Bs[128][40];
    int m0 = blockIdx.y * 128, n0 = blockIdx.x * 128;
    int tid = threadIdx.x, lane = tid & 63, wave = tid >> 6;
    int wr = wave >> 1, wc = wave & 1, quad = lane >> 4, l16 = lane & 15;
    f4 acc[4][4];
    #pragma unroll
    for (int i = 0; i < 4; i++)
        #pragma unroll
        for (int j = 0; j < 4; j++) acc[i][j] = f4{0.f, 0.f, 0.f, 0.f};

    for (int k0 = 0; k0 < K; k0 += 32) {
        __syncthreads();
        #pragma unroll
        for (int i = 0; i < 2; i++) {
            int idx = i * 256 + tid, r = idx >> 2, c = idx & 3;
            *(s8v*)&As[r][c * 8] = *(const s8v*)&A[(size_t)(m0 + r) * K + k0 + c * 8];
            *(s8v*)&Bs[r][c * 8] = *(const s8v*)&BT[(size_t)(n0 + r) * K + k0 + c * 8];
        }
        __syncthreads();
        bf8 af[4], bfr[4];
        #pragma unroll
        for (int i = 0; i < 4; i++) af[i] = *(const bf8*)&As[wr * 64 + i * 16 + l16][quad * 8];
        #pragma unroll
        for (int j = 0; j < 4; j++) bfr[j] = *(const bf8*)&Bs[wc * 64 + j * 16 + l16][quad * 8];
        #pragma unroll
        for (int i = 0; i < 4; i++)
            #pragma unroll
            for (int j = 0; j < 4; j++)
                acc[i][j] = __builtin_amdgcn_mfma_f32_16x16x32_bf16(af[i], bfr[j], acc[i][j], 0, 0, 0);
    }

    #pragma unroll
    for (int i = 0; i < 4; i++)
        #pragma unroll
        for (int j = 0; j < 4; j++) {
            int row0 = m0 + wr * 64 + i * 16 + quad * 4;
            int col = n0 + wc * 64 + j * 16 + l16;
            float bia = bias ? bias[col] : 0.0f;
            #pragma unroll
            for (int r = 0; r < 4; r++) {
                float v = acc[i][j][r] + bia;
                int rw = row0 + r;
                if (mode == 0) {
                    out[(size_t)rw * Nn + col] = f2bf(v);
                } else {
                    int n = rw >> 4, l = rw & 15;
                    out[((size_t)n * Nn + col) * 16 + l] = f2bf(v);
                }
            }
        }
}

// ---------------- per-step kernel ----------------
// 256 wgs x 256 thr. wg (R=wid>>7, C=wid&127): rows [32R,32R+32), h-cols [8C,8C+8).
__global__ __launch_bounds__(256) void k_step(
    int t,
    const float* __restrict__ Afull, const unsigned short* __restrict__ WhT,
    const unsigned short* __restrict__ xwx, const unsigned short* __restrict__ P2,
    const unsigned short* __restrict__ hbR, unsigned short* __restrict__ hbW,
    float* __restrict__ cstate,
    const float* __restrict__ pscoreR, float* __restrict__ pscoreW,
    float* __restrict__ wbuf, int* __restrict__ wflag,
    float* __restrict__ out) {
    __shared__ float wL[512];        // softmax weights: [32 rows][16 l]
    __shared__ float aL[32][33];     // preactivation exchange
    __shared__ float sred2[4][2][8]; // score reduce scratch
    __shared__ float pr[8][32][16];  // partial-score scratch (16 KB)

    const int wid = blockIdx.x;
    const int R = wid >> 7, C = wid & 127;
    const int tid = threadIdx.x, lane = tid & 63, wave = tid >> 6;
    const int quad = lane >> 4, l16 = lane & 15;
    const int rr = wave >> 1, cc = wave & 1;
    const int n_l = tid & 31, jl = tid >> 5;
    const int myn = R * 32 + n_l, myj = C * 8 + jl;

    // ---- phase 0: score wgs reduce partials + softmax + publish ----
    if (wid < 64) {
        const int n = wid;
        float p[8];
        const f4* base = (const f4*)(pscoreR + (size_t)n * 2048 + tid * 8);
        f4 v0 = base[0], v1 = base[1];
        p[0]=v0.x; p[1]=v0.y; p[2]=v0.z; p[3]=v0.w;
        p[4]=v1.x; p[5]=v1.y; p[6]=v1.z; p[7]=v1.w;
        #pragma unroll
        for (int i = 0; i < 8; i++) {
            float v = p[i];
            v += __shfl_down(v, 32, 64); v += __shfl_down(v, 16, 64);
            v += __shfl_down(v, 8, 64);  v += __shfl_down(v, 4, 64);
            v += __shfl_down(v, 2, 64);
            p[i] = v;
        }
        if (lane < 2) {
            #pragma unroll
            for (int i = 0; i < 8; i++) sred2[wave][lane][i] = p[i];
        }
        __syncthreads();
        if (tid == 0) {
            float sc[16]; float mx = -1e30f;
            #pragma unroll
            for (int l = 0; l < 16; l++) {
                sc[l] = (sred2[0][l >> 3][l & 7] + sred2[1][l >> 3][l & 7] +
                         sred2[2][l >> 3][l & 7] + sred2[3][l >> 3][l & 7]) * (1.0f / 32.0f);
                mx = fmaxf(mx, sc[l]);
            }
            float sum = 0.f;
            #pragma unroll
            for (int l = 0; l < 16; l++) { sc[l] = __expf(sc[l] - mx); sum += sc[l]; }
            float inv = 1.0f / sum;
            #pragma unroll
            for (int l = 0; l < 16; l++)
                __hip_atomic_store(&wbuf[n * 16 + l], sc[l] * inv,
                                   __ATOMIC_RELAXED, __HIP_MEMORY_SCOPE_AGENT);
            __hip_atomic_store(&wflag[n], t + 1, __ATOMIC_RELEASE, __HIP_MEMORY_SCOPE_AGENT);
        }
    }

    // ---- phase 1: h@Wh, direct-from-global fragments, one 16x16 tile/wave ----
    const int cl = cc * 16 + l16;
    const int acol = ((cl >> 3) << 10) + C * 8 + (cl & 7);
    const size_t abase = ((size_t)(R * 32 + rr * 16 + l16)) * 1024 + quad * 8;
    const size_t bbase = ((size_t)acol) * 1024 + quad * 8;
    f4 acc = {0.f, 0.f, 0.f, 0.f};
    #pragma unroll 8
    for (int ks = 0; ks < 32; ++ks) {
        bf8 a = *(const bf8*)(hbR + abase + ks * 32);
        bf8 b = *(const bf8*)(WhT + bbase + ks * 32);
        acc = __builtin_amdgcn_mfma_f32_16x16x32_bf16(a, b, acc, 0, 0, 0);
    }

    // ---- phase 2: wait for softmax weights (relaxed poll, one acquire fence) ----
    if (tid < 32) {
        while (__hip_atomic_load(&wflag[R * 32 + tid], __ATOMIC_RELAXED,
                                 __HIP_MEMORY_SCOPE_AGENT) < t + 1)
            __builtin_amdgcn_s_sleep(1);
    }
    __syncthreads();
    __builtin_amdgcn_fence(__ATOMIC_ACQUIRE, "agent");
    wL[tid * 2]     = __hip_atomic_load(&wbuf[R * 512 + tid * 2],
                                        __ATOMIC_RELAXED, __HIP_MEMORY_SCOPE_AGENT);
    wL[tid * 2 + 1] = __hip_atomic_load(&wbuf[R * 512 + tid * 2 + 1],
                                        __ATOMIC_RELAXED, __HIP_MEMORY_SCOPE_AGENT);
    __syncthreads();

    // ---- phase 3: epilogue: + xwx + attention, write preactivations to LDS ----
    #pragma unroll
    for (int r = 0; r < 4; r++) {
        int nl = rr * 16 + quad * 4 + r;
        int n = R * 32 + nl;
        float v = acc[r] + bf2f(xwx[((size_t)n * Tt + t) * FH + acol]);
        const unsigned short* pp = P2 + ((size_t)n * FH + acol) * 16;
        s8v p0 = *(const s8v*)pp;
        s8v p1 = *(const s8v*)(pp + 8);
        float s = 0.f;
        #pragma unroll
        for (int l = 0; l < 8; l++) s += wL[nl * 16 + l] * bf2f((unsigned short)p0[l]);
        #pragma unroll
        for (int l = 0; l < 8; l++) s += wL[nl * 16 + 8 + l] * bf2f((unsigned short)p1[l]);
        aL[nl][cl] = v + s;
    }
    __syncthreads();

    // ---- phase 4: gates + state writes + next-step partial scores ----
    {
        float iv = aL[n_l][jl],      fv = aL[n_l][8 + jl];
        float ov = aL[n_l][16 + jl], gv = aL[n_l][24 + jl];
        float ig = 1.f / (1.f + __expf(-iv));
        float fg = 1.f / (1.f + __expf(-fv));
        float og = 1.f / (1.f + __expf(-ov));
        float gg = tanhf(gv);
        float c = cstate[(size_t)myn * 1024 + myj];
        c = fg * c + ig * gg;
        float hv = og * tanhf(c);
        cstate[(size_t)myn * 1024 + myj] = c;
        out[((size_t)myn * Tt + t) * 1024 + myj] = hv;
        hbW[(size_t)myn * 1024 + myj] = f2bf(hv);

        // partial scores for step t+1: p[l] = hv * A[myn][myj][l]
        const f4* ar = (const f4*)(Afull + ((size_t)myn * 1024 + myj) * 16);
        f4 a0 = ar[0], a1 = ar[1], a2 = ar[2], a3 = ar[3];
        const float* af = (const float*)&a0;
        #pragma unroll
        for (int l = 0; l < 4; l++) pr[jl][n_l][l] = hv * af[l];
        af = (const float*)&a1;
        #pragma unroll
        for (int l = 0; l < 4; l++) pr[jl][n_l][4 + l] = hv * af[l];
        af = (const float*)&a2;
        #pragma unroll
        for (int l = 0; l < 4; l++) pr[jl][n_l][8 + l] = hv * af[l];
        af = (const float*)&a3;
        #pragma unroll
        for (int l = 0; l < 4; l++) pr[jl][n_l][12 + l] = hv * af[l];
    }
    __syncthreads();
    {
        int n2 = tid >> 3, lp = (tid & 7) * 2;
        float s0 = 0.f, s1 = 0.f;
        #pragma unroll
        for (int j = 0; j < 8; j++) { s0 += pr[j][n2][lp]; s1 += pr[j][n2][lp + 1]; }
        float* dst = pscoreW + (((size_t)(R * 32 + n2) * 128) + C) * 16 + lp;
        dst[0] = s0; dst[1] = s1;
    }
}

// ---------------- launch ----------------

extern "C" void kernel_launch(void* const* d_in, const int* in_sizes, int n_in,
                              void* d_out, int out_size, void* d_ws, size_t ws_size,
                              hipStream_t stream) {
    const float* x     = (const float*)d_in[0];   // [64][128][512]
    const float* A     = (const float*)d_in[1];   // [64][1024][16]
    const float* Wx    = (const float*)d_in[2];   // [512][4096]
    const float* Wh    = (const float*)d_in[3];   // [1024][4096]
    const float* Wattn = (const float*)d_in[4];   // [1024][4096]
    const float* b     = (const float*)d_in[5];   // [4096]
    float* out = (float*)d_out;
    char* ws = (char*)d_ws;

    // workspace layout (bytes), total ~100.2 MB
    unsigned short* xbf    = (unsigned short*)(ws);                // 8 MB; reused for P2
    unsigned short* P2     = (unsigned short*)(ws);                // alias (xbf dead by then)
    unsigned short* WxT    = (unsigned short*)(ws + 8388608);      // 4 MB
    unsigned short* WhT    = (unsigned short*)(ws + 12582912);     // 8 MB
    unsigned short* WattnT = (unsigned short*)(ws + 20971520);     // 8 MB
    unsigned short* Afl    = (unsigned short*)(ws + 29360128);     // 2 MB
    unsigned short* xwx    = (unsigned short*)(ws + 31457280);     // 64 MB
    float* cstate          = (float*)(ws + 98566144);              // 256 KB
    unsigned short* hbf    = (unsigned short*)(ws + 98828288);     // 256 KB (x2 ping-pong)
    float* wbuf            = (float*)(ws + 99090432);              // 4 KB
    int* wflag             = (int*)(ws + 99094528);                // 4 KB region
    float* pscore          = (float*)(ws + 99098624);              // 1 MB (x2 ping-pong)

    (void)hipMemsetAsync(wflag, 0, 256, stream);
    (void)hipMemsetAsync(pscore, 0, 524288, stream);   // buffer 0

    k_cast_bf16<<<16384, 256, 0, stream>>>(x, xbf, 4194304);
    k_transpose_bf16<<<dim3(128, 16), 256, 0, stream>>>(Wx, WxT, 512);
    k_transpose_bf16<<<dim3(128, 32), 256, 0, stream>>>(Wh, WhT, 1024);
    k_transpose_bf16<<<dim3(128, 32), 256, 0, stream>>>(Wattn, WattnT, 1024);
    k_afl<<<4096, 256, 0, stream>>>(A, Afl);
    k_init<<<256, 256, 0, stream>>>(A, cstate, hbf);
    k_pscore0<<<64, 256, 0, stream>>>(A, pscore);

    // xwx = x@Wx + b : M=8192, N=4096, K=512
    k_gemm<<<dim3(32, 64), 256, 0, stream>>>(xbf, WxT, b, xwx, 8192, 4096, 512, 0);
    // P2 = Afl@Wattn : M=1024, N=4096, K=1024 (writes over xbf region)
    k_gemm<<<dim3(32, 8), 256, 0, stream>>>(Afl, WattnT, nullptr, P2, 1024, 4096, 1024, 1);

    for (int t = 0; t < Tt; ++t) {
        const unsigned short* hbR = hbf + (size_t)(t & 1) * 65536;
        unsigned short* hbW = hbf + (size_t)((t + 1) & 1) * 65536;
        const float* pscoreR = pscore + (size_t)(t & 1) * 131072;
        float* pscoreW = pscore + (size_t)((t + 1) & 1) * 131072;
        k_step<<<256, 256, 0, stream>>>(t, A, WhT, xwx, P2, hbR, hbW,
                                        cstate, pscoreR, pscoreW, wbuf, wflag, out);
    }
}